// Round 6
// baseline (1440.740 us; speedup 1.0000x reference)
//
#include <hip/hip_runtime.h>
#include <hip/hip_bf16.h>

#define HIDDEN 128
#define NRAD 6

typedef __attribute__((ext_vector_type(8))) short  short8v;
typedef __attribute__((ext_vector_type(4))) float  f32x4;
typedef __attribute__((ext_vector_type(4))) int    int4v;

__device__ __forceinline__ float silu_f(float z) {
    return z / (1.0f + __expf(-z));
}
__device__ __forceinline__ short bf_hi(float v) {
    __hip_bfloat16 b = __float2bfloat16(v);
    return *reinterpret_cast<short*>(&b);
}
__device__ __forceinline__ float bf_to_f(short s) {
    __hip_bfloat16 b = *reinterpret_cast<__hip_bfloat16*>(&s);
    return __bfloat162float(b);
}

// ---------------------------------------------------------------------------
// Kernel A: per-type tables T1/T2 (fp32) + W3 in MFMA A-fragment layout,
// split into bf16 hi/lo.
//
// The A/B k-slot pairing of mfma_f32_16x16x32_bf16 is probed on-device
// (round-5 measured it to be the identity; probe kept — it is cheap,
// self-validating, and future-proofs the packing against layout quirks).
//
//   T1[t][h] = lin_b[h] + sum_k lin_w[h][k]     * emb_w[t][k]
//   T2[t][h] =            sum_k lin_w[h][128+k] * emb_w[t][k]
//   W3F fragment pos = ((kk*8+f)*64 + lane)*8 + j  holds
//       w = lin_w[f*16+(lane&15)][256 + kk*32 + amap[(lane>>4)*8+j]]
//   hi at W3F[pos], lo at W3F[16384+pos]   (bf16 as short)
// ---------------------------------------------------------------------------
__global__ void build_tables(const float* __restrict__ emb_w,
                             const float* __restrict__ lin_w,
                             const float* __restrict__ lin_b,
                             float* __restrict__ T1,
                             float* __restrict__ T2,
                             short* __restrict__ W3F,
                             int n_types)
{
    __shared__ float hv[HIDDEN];
    __shared__ int amap[32];
    int b = blockIdx.x;
    int h = threadIdx.x;          // 0..127
    if (b < n_types) {
        hv[h] = emb_w[b * HIDDEN + h];
        __syncthreads();
        float a1 = lin_b[h];
        float a2 = 0.0f;
        const float* wrow = lin_w + (size_t)h * (3 * HIDDEN);
        #pragma unroll 8
        for (int k = 0; k < HIDDEN; ++k) {
            float e = hv[k];
            a1 = fmaf(wrow[k], e, a1);
            a2 = fmaf(wrow[HIDDEN + k], e, a2);
        }
        T1[b * HIDDEN + h] = a1;
        T2[b * HIDDEN + h] = a2;
    } else {
        // ---- on-device A/B k-slot pairing probe (wave 0 only) ----
        if (h < 64) {
            int lane = h;
            int g = lane >> 4;
            short8v Ap;
            #pragma unroll
            for (int j = 0; j < 8; ++j)
                Ap[j] = (short)((127 + g * 8 + j) << 7);   // bf16 2^(8g+j), exact
            #pragma unroll
            for (int p = 0; p < 32; ++p) {
                short8v Bp;
                #pragma unroll
                for (int j = 0; j < 8; ++j) Bp[j] = 0;
                if (g == (p >> 3)) Bp[p & 7] = (short)0x3F80;  // bf16 1.0
                f32x4 d = {0.f, 0.f, 0.f, 0.f};
                d = __builtin_amdgcn_mfma_f32_16x16x32_bf16(Ap, Bp, d, 0, 0, 0);
                if (lane == 0) {
                    int s = (int)((__builtin_bit_cast(unsigned, d[0]) >> 23) & 0xFF) - 127;
                    amap[s] = p;                         // A-slot s pairs with B-slot p
                }
            }
        }
        __syncthreads();

        int tb = b - n_types;                 // 0..31, 512 fragment slots each
        #pragma unroll
        for (int q = 0; q < 4; ++q) {
            int pos = tb * 512 + q * 128 + h; // 0..16383
            int j  = pos & 7;
            int l  = (pos >> 3) & 63;
            int f  = (pos >> 9) & 7;
            int kk = pos >> 12;
            int hh = f * 16 + (l & 15);
            int k  = kk * 32 + amap[(l >> 4) * 8 + j];
            float w = lin_w[(size_t)hh * (3 * HIDDEN) + 2 * HIDDEN + k];
            short hi = bf_hi(w);
            short lo = bf_hi(w - bf_to_f(hi));
            W3F[pos]          = hi;
            W3F[16384 + pos]  = lo;
        }
    }
}

// ---------------------------------------------------------------------------
// Main edge kernel. Per wave per iteration: 32 edges (two 16-edge MFMA tiles).
//   out[e][h] = silu( T1[x[i[e]]][h] + T2[x[j[e]]][h] + sum_c W3[h][c]*s[e][c] )
//   s[e][c] = silu(rbf[e] . rw[c] + rb[c]) computed per-lane in registers,
//   split to bf16 hi/lo as the MFMA B operand (N = edge).
// ---------------------------------------------------------------------------
__global__ __launch_bounds__(512, 2)
void edge_kernel(const int*   __restrict__ x,
                 const float* __restrict__ rbf,
                 const int*   __restrict__ ei,
                 const int*   __restrict__ ej,
                 const float* __restrict__ rw,    // [128][6]
                 const float* __restrict__ rb,    // [128]
                 const float* __restrict__ T1,
                 const float* __restrict__ T2,
                 const short* __restrict__ W3F,   // fragments, hi then lo
                 float*       __restrict__ out,
                 int E)
{
    __shared__ short W3s[32768];                 // 64 KB: hi [0,16384), lo [16384,32768)

    // one-time stage, coalesced int4
    {
        const int4v* g = (const int4v*)W3F;
        int4v* s = (int4v*)W3s;
        for (int idx = threadIdx.x; idx < 4096; idx += 512) s[idx] = g[idx];
    }
    __syncthreads();

    const int tid  = threadIdx.x;
    const int lane = tid & 63;
    const int wv   = tid >> 6;
    const int eh   = lane & 15;   // edge within tile (MFMA N / C-col)
    const int g4   = lane >> 4;   // k-group / C-row quad

    const int npairs = (E + 31) >> 5;

    for (int pair = blockIdx.x * 8 + wv; pair < npairs; pair += gridDim.x * 8) {
        const int e0 = pair << 5;
        const int eA = e0 + eh;
        const int eB = e0 + 16 + eh;
        const int eAc = (eA < E) ? eA : (E - 1);
        const int eBc = (eB < E) ? eB : (E - 1);

        // issue gather-index chains early (consumed in the epilogue)
        const int xiA = x[ei[eAc]];
        const int xjA = x[ej[eAc]];
        const int xiB = x[ei[eBc]];
        const int xjB = x[ej[eBc]];

        // per-lane rbf rows for its two edges
        float rvA[6], rvB[6];
        {
            const float2* p = (const float2*)(rbf + (size_t)eAc * NRAD);
            float2 a0 = p[0], a1 = p[1], a2 = p[2];
            rvA[0]=a0.x; rvA[1]=a0.y; rvA[2]=a1.x; rvA[3]=a1.y; rvA[4]=a2.x; rvA[5]=a2.y;
            const float2* q = (const float2*)(rbf + (size_t)eBc * NRAD);
            float2 b0 = q[0], b1 = q[1], b2 = q[2];
            rvB[0]=b0.x; rvB[1]=b0.y; rvB[2]=b1.x; rvB[3]=b1.y; rvB[4]=b2.x; rvB[5]=b2.y;
        }

        // rbf hidden layer -> bf16 hi/lo B-fragments, all in registers
        short8v Bh[2][4], Bl[2][4];
        #pragma unroll
        for (int kk = 0; kk < 4; ++kk) {
            const int c0 = kk * 32 + g4 * 8;
            float rwv[48];
            {
                const f32x4* p = (const f32x4*)(rw + c0 * NRAD);  // 192B contiguous
                #pragma unroll
                for (int q = 0; q < 12; ++q) {
                    f32x4 v = p[q];
                    rwv[q*4+0] = v[0]; rwv[q*4+1] = v[1]; rwv[q*4+2] = v[2]; rwv[q*4+3] = v[3];
                }
            }
            float rbv[8];
            {
                const f32x4* p = (const f32x4*)(rb + c0);
                f32x4 v0 = p[0], v1 = p[1];
                rbv[0]=v0[0]; rbv[1]=v0[1]; rbv[2]=v0[2]; rbv[3]=v0[3];
                rbv[4]=v1[0]; rbv[5]=v1[1]; rbv[6]=v1[2]; rbv[7]=v1[3];
            }
            #pragma unroll
            for (int j = 0; j < 8; ++j) {
                float zA = rbv[j], zB = rbv[j];
                #pragma unroll
                for (int r = 0; r < NRAD; ++r) {
                    float wgt = rwv[j * NRAD + r];
                    zA = fmaf(wgt, rvA[r], zA);
                    zB = fmaf(wgt, rvB[r], zB);
                }
                float sA = silu_f(zA);
                float sB = silu_f(zB);
                short ha = bf_hi(sA);
                short hb = bf_hi(sB);
                Bh[0][kk][j] = ha;
                Bl[0][kk][j] = bf_hi(sA - bf_to_f(ha));
                Bh[1][kk][j] = hb;
                Bl[1][kk][j] = bf_hi(sB - bf_to_f(hb));
            }
        }

        // MFMA: acc[t][f] (C row = h-quad, col = edge), 3-term split
        f32x4 acc[2][8];
        #pragma unroll
        for (int t = 0; t < 2; ++t)
            #pragma unroll
            for (int f = 0; f < 8; ++f)
                acc[t][f] = (f32x4){0.f, 0.f, 0.f, 0.f};

        const short8v* Ap = (const short8v*)W3s;
        #pragma unroll
        for (int kk = 0; kk < 4; ++kk) {
            #pragma unroll
            for (int f = 0; f < 8; ++f) {
                short8v Ah = Ap[(kk * 8 + f) * 64 + lane];
                // hi region is 16384 shorts = 2048 short8v units (round-5 bug: 1024)
                short8v Al = Ap[2048 + (kk * 8 + f) * 64 + lane];
                acc[0][f] = __builtin_amdgcn_mfma_f32_16x16x32_bf16(Ah, Bh[0][kk], acc[0][f], 0, 0, 0);
                acc[0][f] = __builtin_amdgcn_mfma_f32_16x16x32_bf16(Al, Bh[0][kk], acc[0][f], 0, 0, 0);
                acc[0][f] = __builtin_amdgcn_mfma_f32_16x16x32_bf16(Ah, Bl[0][kk], acc[0][f], 0, 0, 0);
                acc[1][f] = __builtin_amdgcn_mfma_f32_16x16x32_bf16(Ah, Bh[1][kk], acc[1][f], 0, 0, 0);
                acc[1][f] = __builtin_amdgcn_mfma_f32_16x16x32_bf16(Al, Bh[1][kk], acc[1][f], 0, 0, 0);
                acc[1][f] = __builtin_amdgcn_mfma_f32_16x16x32_bf16(Ah, Bl[1][kk], acc[1][f], 0, 0, 0);
            }
        }

        // epilogue: + T1[x[i]] + T2[x[j]], silu, float4 stores
        #pragma unroll
        for (int t = 0; t < 2; ++t) {
            const int el = (t == 0) ? eA : eB;
            const int xi = (t == 0) ? xiA : xiB;
            const int xj = (t == 0) ? xjA : xjB;
            const f32x4* t1p = (const f32x4*)(T1 + (size_t)xi * HIDDEN) + g4;
            const f32x4* t2p = (const f32x4*)(T2 + (size_t)xj * HIDDEN) + g4;
            if (el < E) {
                f32x4* op = (f32x4*)(out + (size_t)el * HIDDEN) + g4;
                #pragma unroll
                for (int f = 0; f < 8; ++f) {
                    f32x4 v1 = t1p[f * 4];
                    f32x4 v2 = t2p[f * 4];
                    f32x4 a  = acc[t][f];
                    f32x4 o;
                    #pragma unroll
                    for (int r = 0; r < 4; ++r)
                        o[r] = silu_f(a[r] + v1[r] + v2[r]);
                    op[f * 4] = o;
                }
            }
        }
    }
}

// ---------------------------------------------------------------------------
extern "C" void kernel_launch(void* const* d_in, const int* in_sizes, int n_in,
                              void* d_out, int out_size, void* d_ws, size_t ws_size,
                              hipStream_t stream)
{
    const int*   x         = (const int*)  d_in[0];
    const float* rbf       = (const float*)d_in[1];
    const int*   ei        = (const int*)  d_in[2];
    const int*   ej        = (const int*)  d_in[3];
    const float* emb_w     = (const float*)d_in[4];
    const float* lin_rbf_w = (const float*)d_in[5];
    const float* lin_rbf_b = (const float*)d_in[6];
    const float* lin_w     = (const float*)d_in[7];
    const float* lin_b     = (const float*)d_in[8];

    int E  = in_sizes[2];                 // edge count
    int NT = in_sizes[4] / HIDDEN;        // number of node types (95)

    // workspace: T1 | T2 | W3F(hi,lo bf16 fragments)  -> 2*NT*128*4 + 65536 B
    float* T1  = (float*)d_ws;
    float* T2  = T1 + (size_t)NT * HIDDEN;
    short* W3F = (short*)(T2 + (size_t)NT * HIDDEN);

    hipLaunchKernelGGL(build_tables, dim3(NT + 32), dim3(HIDDEN), 0, stream,
                       emb_w, lin_w, lin_b, T1, T2, W3F, NT);

    hipLaunchKernelGGL(edge_kernel, dim3(512), dim3(512), 0, stream,
                       x, rbf, ei, ej, lin_rbf_w, lin_rbf_b,
                       T1, T2, W3F, (float*)d_out, E);
}